// Round 2
// baseline (1149.281 us; speedup 1.0000x reference)
//
#include <hip/hip_runtime.h>
#include <hip/hip_bf16.h>
#include <math.h>

typedef float f4 __attribute__((ext_vector_type(4)));
typedef float f32x4 __attribute__((ext_vector_type(4)));
typedef _Float16 h4 __attribute__((ext_vector_type(4)));
typedef _Float16 h8 __attribute__((ext_vector_type(8)));

#define D_ 1024
#define DFF_ 4096
#define L_ 2
#define RF_ 16
#define NTOK_ 1152            // B * NC = 32*36
#define M_ 18432              // NTOK_ * RF_

// ---------------- elementwise ----------------
__global__ __launch_bounds__(256) void k_init_x(float* __restrict__ x, const float* __restrict__ rfq) {
  int i = blockIdx.x * 256 + threadIdx.x;   // float4 index
  int c = i & 255;                          // D/4 = 256
  int m = i >> 8;
  ((f4*)x)[i] = ((const f4*)rfq)[((m & 15) << 8) | c];   // row m -> rf row m%16
}

__global__ __launch_bounds__(256) void k_cvt(const float* __restrict__ in, _Float16* __restrict__ out) {
  int i = blockIdx.x * 256 + threadIdx.x;
  f4 v = ((const f4*)in)[i];
  ((h4*)out)[i] = __builtin_convertvector(v, h4);
}

__global__ __launch_bounds__(256) void k_bcast_add(float* __restrict__ x, const float* __restrict__ att) {
  int i = blockIdx.x * 256 + threadIdx.x;
  int c = i & 255;
  int m = i >> 8;
  int n = m >> 4;                           // m / RF
  f4 v = ((f4*)x)[i];
  f4 a = ((const f4*)att)[(n << 8) | c];
  ((f4*)x)[i] = v + a;
}

// W (R x C, f32, row-major) -> WT (C x R, f16)
__global__ __launch_bounds__(256) void k_transpose_cvt(const float* __restrict__ W, _Float16* __restrict__ WT,
                                                       int R, int C) {
  __shared__ float t[32][33];
  int c0 = blockIdx.x * 32, r0 = blockIdx.y * 32;
  int cc = threadIdx.x & 31, rr = threadIdx.x >> 5;   // rr: 0..7
  #pragma unroll
  for (int p = 0; p < 32; p += 8)
    t[rr + p][cc] = W[(size_t)(r0 + rr + p) * C + (c0 + cc)];
  __syncthreads();
  #pragma unroll
  for (int p = 0; p < 32; p += 8)
    WT[(size_t)(c0 + rr + p) * R + (r0 + cc)] = (_Float16)t[cc][rr + p];
}

// ---------------- layernorm ----------------
__device__ inline float block_sum256(float v) {
  __shared__ float red[4];
  #pragma unroll
  for (int o = 32; o > 0; o >>= 1) v += __shfl_down(v, o);
  int w = threadIdx.x >> 6;
  if ((threadIdx.x & 63) == 0) red[w] = v;
  __syncthreads();
  float r = red[0] + red[1] + red[2] + red[3];
  __syncthreads();
  return r;
}

template<int F16OUT>
__global__ __launch_bounds__(256) void k_ln(const float* __restrict__ x, const float* __restrict__ s,
                                            const float* __restrict__ b, void* __restrict__ out) {
  size_t row = blockIdx.x;
  int t = threadIdx.x;
  f4 v = ((const f4*)(x + row * D_))[t];
  float mean = block_sum256(v.x + v.y + v.z + v.w) * (1.0f / D_);
  f4 d = v - mean;
  float var = block_sum256(d.x*d.x + d.y*d.y + d.z*d.z + d.w*d.w) * (1.0f / D_);
  float rstd = rsqrtf(var + 1e-5f);
  f4 sc = ((const f4*)s)[t];
  f4 bb = ((const f4*)b)[t];
  f4 r = d * rstd * sc + bb;
  if (F16OUT) ((h4*)out)[row * (D_/4) + t] = __builtin_convertvector(r, h4);
  else        ((f4*)out)[row * (D_/4) + t] = r;
}

// ---------------- GEMM:  C(MxN) = A(MxK,f16) @ Bt(NxK,f16)^T + bias ----------------
// EPI: 0 -> f16 store, 1 -> f32 store, 2 -> gelu(exact) f16 store, 3 -> += into f32
template<int EPI>
__global__ __launch_bounds__(256) void k_gemm(const _Float16* __restrict__ A,
                                              const _Float16* __restrict__ Bt,
                                              const float* __restrict__ bias,
                                              void* __restrict__ out,
                                              int M, int N, int K) {
  __shared__ __align__(16) _Float16 As[128][72];   // 144B row stride: 16B aligned, conflict-benign
  __shared__ __align__(16) _Float16 Bs[128][72];
  const int tid = threadIdx.x;
  const int lane = tid & 63;
  const int w = tid >> 6;
  const int wr = (w >> 1) << 6;       // wave row offset in tile (0/64)
  const int wc = (w & 1) << 6;        // wave col offset (0/64)
  const int bm = blockIdx.y << 7;
  const int bn = blockIdx.x << 7;
  const int g = lane >> 4;            // 0..3
  const int lr = lane & 15;
  const int srow = tid >> 3;          // staging: 0..31
  const int scol = (tid & 7) << 3;    // 0..56

  f32x4 acc[4][4];
  #pragma unroll
  for (int m = 0; m < 4; ++m)
    #pragma unroll
    for (int n = 0; n < 4; ++n)
      acc[m][n] = (f32x4){0.f, 0.f, 0.f, 0.f};

  const _Float16* Ab = A + (size_t)bm * K;
  const _Float16* Bb = Bt + (size_t)bn * K;

  for (int kt = 0; kt < K; kt += 64) {
    #pragma unroll
    for (int p = 0; p < 4; ++p) {
      int r = (p << 5) + srow;
      *(h8*)(&As[r][scol]) = *(const h8*)(Ab + (size_t)r * K + kt + scol);
      *(h8*)(&Bs[r][scol]) = *(const h8*)(Bb + (size_t)r * K + kt + scol);
    }
    __syncthreads();
    #pragma unroll
    for (int kk = 0; kk < 64; kk += 32) {
      h8 af[4], bf[4];
      #pragma unroll
      for (int m = 0; m < 4; ++m) af[m] = *(const h8*)(&As[wr + (m << 4) + lr][kk + (g << 3)]);
      #pragma unroll
      for (int n = 0; n < 4; ++n) bf[n] = *(const h8*)(&Bs[wc + (n << 4) + lr][kk + (g << 3)]);
      #pragma unroll
      for (int m = 0; m < 4; ++m)
        #pragma unroll
        for (int n = 0; n < 4; ++n)
          acc[m][n] = __builtin_amdgcn_mfma_f32_16x16x32_f16(af[m], bf[n], acc[m][n], 0, 0, 0);
    }
    __syncthreads();
  }

  #pragma unroll
  for (int n = 0; n < 4; ++n) {
    int col = bn + wc + (n << 4) + lr;
    float bval = bias[col];
    #pragma unroll
    for (int m = 0; m < 4; ++m) {
      #pragma unroll
      for (int j = 0; j < 4; ++j) {
        int row = bm + wr + (m << 4) + (g << 2) + j;   // C/D: col=lane&15, row=(lane>>4)*4+j
        float v = acc[m][n][j] + bval;
        size_t off = (size_t)row * N + col;
        if constexpr (EPI == 0)      ((_Float16*)out)[off] = (_Float16)v;
        else if constexpr (EPI == 1) ((float*)out)[off] = v;
        else if constexpr (EPI == 2) ((_Float16*)out)[off] =
            (_Float16)(0.5f * v * (1.0f + erff(v * 0.70710678118654752f)));
        else                         ((float*)out)[off] += v;
      }
    }
  }
}

// ---------------- launch ----------------
extern "C" void kernel_launch(void* const* d_in, const int* in_sizes, int n_in,
                              void* d_out, int out_size, void* d_ws, size_t ws_size,
                              hipStream_t stream) {
  const float* ct   = (const float*)d_in[0];
  const float* rfq  = (const float*)d_in[1];
  // d_in[2..7]: ln1_s, ln1_b, wq, bq, wk, bk -- dead (softmax over kv_len=1 is identically 1)
  const float* wv   = (const float*)d_in[8];
  const float* bv   = (const float*)d_in[9];
  const float* wo   = (const float*)d_in[10];
  const float* bo   = (const float*)d_in[11];
  const float* ln2s = (const float*)d_in[12];
  const float* ln2b = (const float*)d_in[13];
  const float* w1   = (const float*)d_in[14];
  const float* b1   = (const float*)d_in[15];
  const float* w2   = (const float*)d_in[16];
  const float* b2   = (const float*)d_in[17];
  const float* lnfs = (const float*)d_in[18];
  const float* lnfb = (const float*)d_in[19];

  // fp32 residual stream lives in d_out (exactly M_ x D_ floats); final LN is in-place.
  float* x = (float*)d_out;

  // ---- workspace budget (adaptive chunking of the MLP over M) ----
  char* p = (char*)d_ws;
  auto alloc = [&](size_t bytes) { char* r = p; p += (bytes + 255) & ~(size_t)255; return r; };
  _Float16* kvh = (_Float16*)alloc((size_t)NTOK_ * D_ * 2);
  _Float16* Vh  = (_Float16*)alloc((size_t)NTOK_ * D_ * 2);
  float*    att = (float*)   alloc((size_t)NTOK_ * D_ * 4);
  _Float16* wvt = (_Float16*)alloc((size_t)D_ * D_ * 2);      // per-layer, reused
  _Float16* wot = (_Float16*)alloc((size_t)D_ * D_ * 2);
  _Float16* w1t = (_Float16*)alloc((size_t)D_ * DFF_ * 2);
  _Float16* w2t = (_Float16*)alloc((size_t)DFF_ * D_ * 2);
  size_t persist = (size_t)(p - (char*)d_ws);

  int MC = 1152;                                              // minimum chunk (fits ~42 MB)
  const int cand[5] = {18432, 9216, 4608, 2304, 1152};
  for (int i = 0; i < 5; ++i) {
    size_t need = persist + ((size_t)cand[i] * D_ * 2 + 256) + ((size_t)cand[i] * DFF_ * 2 + 256) + 1024;
    if (need <= ws_size) { MC = cand[i]; break; }
  }
  _Float16* hh  = (_Float16*)alloc((size_t)MC * D_ * 2);      // LN2 output chunk
  _Float16* H1h = (_Float16*)alloc((size_t)MC * DFF_ * 2);    // gelu output chunk

  k_init_x<<<M_ * D_ / 4 / 256, 256, 0, stream>>>(x, rfq);
  k_cvt<<<NTOK_ * D_ / 4 / 256, 256, 0, stream>>>(ct, kvh);

  for (int l = 0; l < L_; ++l) {
    // per-layer weight transpose+convert (f32 -> f16, N x K layout)
    k_transpose_cvt<<<dim3(D_/32, D_/32), 256, 0, stream>>>(wv + (size_t)l*D_*D_,   wvt, D_, D_);
    k_transpose_cvt<<<dim3(D_/32, D_/32), 256, 0, stream>>>(wo + (size_t)l*D_*D_,   wot, D_, D_);
    k_transpose_cvt<<<dim3(DFF_/32, D_/32), 256, 0, stream>>>(w1 + (size_t)l*D_*DFF_, w1t, D_, DFF_);
    k_transpose_cvt<<<dim3(D_/32, DFF_/32), 256, 0, stream>>>(w2 + (size_t)l*DFF_*D_, w2t, DFF_, D_);

    // attention (collapsed, softmax over kv_len=1 == 1): att = (kv@wv+bv)@wo+bo ; x[n*16+r] += att[n]
    k_gemm<0><<<dim3(D_/128, NTOK_/128), 256, 0, stream>>>(kvh, wvt, bv + l*D_, Vh, NTOK_, D_, D_);
    k_gemm<1><<<dim3(D_/128, NTOK_/128), 256, 0, stream>>>(Vh,  wot, bo + l*D_, att, NTOK_, D_, D_);
    k_bcast_add<<<M_ * D_ / 4 / 256, 256, 0, stream>>>(x, att);

    // MLP, chunked over M to fit workspace
    for (int m0 = 0; m0 < M_; m0 += MC) {
      k_ln<1><<<MC, 256, 0, stream>>>(x + (size_t)m0 * D_, ln2s + l*D_, ln2b + l*D_, hh);
      k_gemm<2><<<dim3(DFF_/128, MC/128), 256, 0, stream>>>(hh,  w1t, b1 + l*DFF_, H1h, MC, DFF_, D_);
      k_gemm<3><<<dim3(D_/128, MC/128), 256, 0, stream>>>(H1h, w2t, b2 + l*D_, x + (size_t)m0 * D_, MC, D_, DFF_);
    }
  }
  k_ln<0><<<M_, 256, 0, stream>>>(x, lnfs, lnfb, d_out);
}

// Round 3
// 1141.783 us; speedup vs baseline: 1.0066x; 1.0066x over previous
//
#include <hip/hip_runtime.h>
#include <hip/hip_bf16.h>
#include <math.h>

typedef float f4 __attribute__((ext_vector_type(4)));
typedef float f32x4 __attribute__((ext_vector_type(4)));
typedef _Float16 h4 __attribute__((ext_vector_type(4)));
typedef _Float16 h8 __attribute__((ext_vector_type(8)));

#define D_ 1024
#define DFF_ 4096
#define L_ 2
#define RF_ 16
#define NTOK_ 1152            // B * NC = 32*36
#define M_ 18432              // NTOK_ * RF_

__device__ __forceinline__ void gload_lds16(const void* g, void* l) {
  __builtin_amdgcn_global_load_lds((const __attribute__((address_space(1))) void*)g,
                                   (__attribute__((address_space(3))) void*)l, 16, 0, 0);
}

// ---------------- elementwise ----------------
__global__ __launch_bounds__(256) void k_init_x(float* __restrict__ x, const float* __restrict__ rfq) {
  int i = blockIdx.x * 256 + threadIdx.x;   // float4 index
  int c = i & 255;                          // D/4 = 256
  int m = i >> 8;
  ((f4*)x)[i] = ((const f4*)rfq)[((m & 15) << 8) | c];   // row m -> rf row m%16
}

__global__ __launch_bounds__(256) void k_cvt(const float* __restrict__ in, _Float16* __restrict__ out) {
  int i = blockIdx.x * 256 + threadIdx.x;
  f4 v = ((const f4*)in)[i];
  ((h4*)out)[i] = __builtin_convertvector(v, h4);
}

__global__ __launch_bounds__(256) void k_bcast_add(float* __restrict__ x, const float* __restrict__ att) {
  int i = blockIdx.x * 256 + threadIdx.x;
  int c = i & 255;
  int m = i >> 8;
  int n = m >> 4;                           // m / RF
  f4 v = ((f4*)x)[i];
  f4 a = ((const f4*)att)[(n << 8) | c];
  ((f4*)x)[i] = v + a;
}

// W (R x C, f32, row-major) -> WT (C x R, f16)
__global__ __launch_bounds__(256) void k_transpose_cvt(const float* __restrict__ W, _Float16* __restrict__ WT,
                                                       int R, int C) {
  __shared__ float t[32][33];
  int c0 = blockIdx.x * 32, r0 = blockIdx.y * 32;
  int cc = threadIdx.x & 31, rr = threadIdx.x >> 5;   // rr: 0..7
  #pragma unroll
  for (int p = 0; p < 32; p += 8)
    t[rr + p][cc] = W[(size_t)(r0 + rr + p) * C + (c0 + cc)];
  __syncthreads();
  #pragma unroll
  for (int p = 0; p < 32; p += 8)
    WT[(size_t)(c0 + rr + p) * R + (r0 + cc)] = (_Float16)t[cc][rr + p];
}

// ---------------- layernorm ----------------
__device__ inline float block_sum256(float v) {
  __shared__ float red[4];
  #pragma unroll
  for (int o = 32; o > 0; o >>= 1) v += __shfl_down(v, o);
  int w = threadIdx.x >> 6;
  if ((threadIdx.x & 63) == 0) red[w] = v;
  __syncthreads();
  float r = red[0] + red[1] + red[2] + red[3];
  __syncthreads();
  return r;
}

template<int F16OUT>
__global__ __launch_bounds__(256) void k_ln(const float* __restrict__ x, const float* __restrict__ s,
                                            const float* __restrict__ b, void* __restrict__ out) {
  size_t row = blockIdx.x;
  int t = threadIdx.x;
  f4 v = ((const f4*)(x + row * D_))[t];
  float mean = block_sum256(v.x + v.y + v.z + v.w) * (1.0f / D_);
  f4 d = v - mean;
  float var = block_sum256(d.x*d.x + d.y*d.y + d.z*d.z + d.w*d.w) * (1.0f / D_);
  float rstd = rsqrtf(var + 1e-5f);
  f4 sc = ((const f4*)s)[t];
  f4 bb = ((const f4*)b)[t];
  f4 r = d * rstd * sc + bb;
  if (F16OUT) ((h4*)out)[row * (D_/4) + t] = __builtin_convertvector(r, h4);
  else        ((f4*)out)[row * (D_/4) + t] = r;
}

// ---------------- GEMM:  C(MxN) = A(MxK,f16) @ Bt(NxK,f16)^T + bias ----------------
// m97 structure: global_load_lds width=16 into linear [128][64] LDS, BK=64,
// both-sides XOR swizzle (physical 16B-slot = logical ^ (row&7)) so the
// stride-128B ds_read_b128 pattern lands 2 lanes/bank (free) instead of 16-way.
// EPI: 0 -> f16 store, 1 -> f32 store, 2 -> gelu(exact) f16 store, 3 -> += into f32
template<int EPI>
__global__ __launch_bounds__(256) void k_gemm(const _Float16* __restrict__ A,
                                              const _Float16* __restrict__ Bt,
                                              const float* __restrict__ bias,
                                              void* __restrict__ out,
                                              int M, int N, int K) {
  __shared__ __align__(16) _Float16 As[128][64];   // linear: global_load_lds writes base+lane*16
  __shared__ __align__(16) _Float16 Bs[128][64];
  const int tid = threadIdx.x;
  const int lane = tid & 63;
  const int w = tid >> 6;
  const int wr = (w >> 1) << 6;       // wave row offset in tile (0/64)
  const int wc = (w & 1) << 6;        // wave col offset (0/64)
  const int bm = blockIdx.y << 7;
  const int bn = blockIdx.x << 7;
  const int g = lane >> 4;            // 0..3
  const int lr = lane & 15;
  const int x7 = lr & 7;              // read-side swizzle key (row&7 == lr&7)
  // staging: lane covers row r0+(lane>>3), 16B slot (lane&7); source column is
  // inverse-swizzled so a linear LDS write yields swizzled physical layout.
  const int srow = lane >> 3;
  const int scl8 = (((lane & 7) ^ (srow & 7)) << 3);   // halves offset in row

  f32x4 acc[4][4];
  #pragma unroll
  for (int m = 0; m < 4; ++m)
    #pragma unroll
    for (int n = 0; n < 4; ++n)
      acc[m][n] = (f32x4){0.f, 0.f, 0.f, 0.f};

  const _Float16* Ab = A + (size_t)bm * K;
  const _Float16* Bb = Bt + (size_t)bn * K;

  for (int kt = 0; kt < K; kt += 64) {
    #pragma unroll
    for (int p = 0; p < 4; ++p) {
      int r0 = ((w << 2) + p) << 3;                    // wave-uniform LDS base row
      int r = r0 + srow;
      gload_lds16(Ab + (size_t)r * K + kt + scl8, &As[r0][0]);
      gload_lds16(Bb + (size_t)r * K + kt + scl8, &Bs[r0][0]);
    }
    __syncthreads();                                   // drains vmcnt before LDS reads
    #pragma unroll
    for (int kk8 = 0; kk8 < 8; kk8 += 4) {             // two K=32 sub-steps
      h8 af[4], bf[4];
      const int c8 = ((kk8 + g) ^ x7) << 3;            // swizzled read slot (halves)
      #pragma unroll
      for (int m = 0; m < 4; ++m) af[m] = *(const h8*)(&As[wr + (m << 4) + lr][c8]);
      #pragma unroll
      for (int n = 0; n < 4; ++n) bf[n] = *(const h8*)(&Bs[wc + (n << 4) + lr][c8]);
      #pragma unroll
      for (int m = 0; m < 4; ++m)
        #pragma unroll
        for (int n = 0; n < 4; ++n)
          acc[m][n] = __builtin_amdgcn_mfma_f32_16x16x32_f16(af[m], bf[n], acc[m][n], 0, 0, 0);
    }
    __syncthreads();
  }

  #pragma unroll
  for (int n = 0; n < 4; ++n) {
    int col = bn + wc + (n << 4) + lr;
    float bval = bias[col];
    #pragma unroll
    for (int m = 0; m < 4; ++m) {
      #pragma unroll
      for (int j = 0; j < 4; ++j) {
        int row = bm + wr + (m << 4) + (g << 2) + j;   // C/D: col=lane&15, row=(lane>>4)*4+j
        float v = acc[m][n][j] + bval;
        size_t off = (size_t)row * N + col;
        if constexpr (EPI == 0)      ((_Float16*)out)[off] = (_Float16)v;
        else if constexpr (EPI == 1) ((float*)out)[off] = v;
        else if constexpr (EPI == 2) ((_Float16*)out)[off] =
            (_Float16)(0.5f * v * (1.0f + erff(v * 0.70710678118654752f)));
        else                         ((float*)out)[off] += v;
      }
    }
  }
}

// ---------------- launch ----------------
extern "C" void kernel_launch(void* const* d_in, const int* in_sizes, int n_in,
                              void* d_out, int out_size, void* d_ws, size_t ws_size,
                              hipStream_t stream) {
  const float* ct   = (const float*)d_in[0];
  const float* rfq  = (const float*)d_in[1];
  // d_in[2..7]: ln1_s, ln1_b, wq, bq, wk, bk -- dead (softmax over kv_len=1 is identically 1)
  const float* wv   = (const float*)d_in[8];
  const float* bv   = (const float*)d_in[9];
  const float* wo   = (const float*)d_in[10];
  const float* bo   = (const float*)d_in[11];
  const float* ln2s = (const float*)d_in[12];
  const float* ln2b = (const float*)d_in[13];
  const float* w1   = (const float*)d_in[14];
  const float* b1   = (const float*)d_in[15];
  const float* w2   = (const float*)d_in[16];
  const float* b2   = (const float*)d_in[17];
  const float* lnfs = (const float*)d_in[18];
  const float* lnfb = (const float*)d_in[19];

  // fp32 residual stream lives in d_out (exactly M_ x D_ floats); final LN is in-place.
  float* x = (float*)d_out;

  // ---- workspace budget (adaptive chunking of the MLP over M) ----
  char* p = (char*)d_ws;
  auto alloc = [&](size_t bytes) { char* r = p; p += (bytes + 255) & ~(size_t)255; return r; };
  _Float16* kvh = (_Float16*)alloc((size_t)NTOK_ * D_ * 2);
  _Float16* Vh  = (_Float16*)alloc((size_t)NTOK_ * D_ * 2);
  float*    att = (float*)   alloc((size_t)NTOK_ * D_ * 4);
  _Float16* wvt = (_Float16*)alloc((size_t)D_ * D_ * 2);      // per-layer, reused
  _Float16* wot = (_Float16*)alloc((size_t)D_ * D_ * 2);
  _Float16* w1t = (_Float16*)alloc((size_t)D_ * DFF_ * 2);
  _Float16* w2t = (_Float16*)alloc((size_t)DFF_ * D_ * 2);
  size_t persist = (size_t)(p - (char*)d_ws);

  int MC = 1152;                                              // minimum chunk (fits ~42 MB)
  const int cand[5] = {18432, 9216, 4608, 2304, 1152};
  for (int i = 0; i < 5; ++i) {
    size_t need = persist + ((size_t)cand[i] * D_ * 2 + 256) + ((size_t)cand[i] * DFF_ * 2 + 256) + 1024;
    if (need <= ws_size) { MC = cand[i]; break; }
  }
  _Float16* hh  = (_Float16*)alloc((size_t)MC * D_ * 2);      // LN2 output chunk
  _Float16* H1h = (_Float16*)alloc((size_t)MC * DFF_ * 2);    // gelu output chunk

  k_init_x<<<M_ * D_ / 4 / 256, 256, 0, stream>>>(x, rfq);
  k_cvt<<<NTOK_ * D_ / 4 / 256, 256, 0, stream>>>(ct, kvh);

  for (int l = 0; l < L_; ++l) {
    // per-layer weight transpose+convert (f32 -> f16, N x K layout)
    k_transpose_cvt<<<dim3(D_/32, D_/32), 256, 0, stream>>>(wv + (size_t)l*D_*D_,   wvt, D_, D_);
    k_transpose_cvt<<<dim3(D_/32, D_/32), 256, 0, stream>>>(wo + (size_t)l*D_*D_,   wot, D_, D_);
    k_transpose_cvt<<<dim3(DFF_/32, D_/32), 256, 0, stream>>>(w1 + (size_t)l*D_*DFF_, w1t, D_, DFF_);
    k_transpose_cvt<<<dim3(D_/32, DFF_/32), 256, 0, stream>>>(w2 + (size_t)l*DFF_*D_, w2t, DFF_, D_);

    // attention (collapsed, softmax over kv_len=1 == 1): att = (kv@wv+bv)@wo+bo ; x[n*16+r] += att[n]
    k_gemm<0><<<dim3(D_/128, NTOK_/128), 256, 0, stream>>>(kvh, wvt, bv + l*D_, Vh, NTOK_, D_, D_);
    k_gemm<1><<<dim3(D_/128, NTOK_/128), 256, 0, stream>>>(Vh,  wot, bo + l*D_, att, NTOK_, D_, D_);
    k_bcast_add<<<M_ * D_ / 4 / 256, 256, 0, stream>>>(x, att);

    // MLP, chunked over M to fit workspace
    for (int m0 = 0; m0 < M_; m0 += MC) {
      k_ln<1><<<MC, 256, 0, stream>>>(x + (size_t)m0 * D_, ln2s + l*D_, ln2b + l*D_, hh);
      k_gemm<2><<<dim3(DFF_/128, MC/128), 256, 0, stream>>>(hh,  w1t, b1 + l*DFF_, H1h, MC, DFF_, D_);
      k_gemm<3><<<dim3(D_/128, MC/128), 256, 0, stream>>>(H1h, w2t, b2 + l*D_, x + (size_t)m0 * D_, MC, D_, DFF_);
    }
  }
  k_ln<0><<<M_, 256, 0, stream>>>(x, lnfs, lnfb, d_out);
}